// Round 8
// baseline (3563.071 us; speedup 1.0000x reference)
//
#include <hip/hip_runtime.h>
#include <hip/hip_fp16.h>
#include <stdint.h>

#define NB   64      // batch
#define NT   2048    // time steps
#define NF   256     // input features
#define NH   256     // hidden
#define NG   768     // 3*NH

typedef unsigned int u32;
typedef _Float16 f16;
typedef f16 half2v __attribute__((ext_vector_type(2)));

__device__ __forceinline__ u32 packpair(float a, float b) {
    return __builtin_bit_cast(u32, __builtin_amdgcn_cvt_pkrtz(a, b));   // v_cvt_pkrtz_f16_f32
}
__device__ __forceinline__ float fdot2u(u32 w, u32 h, float acc) {      // f32-acc dot2
#if __has_builtin(__builtin_amdgcn_fdot2)
    return __builtin_amdgcn_fdot2(__builtin_bit_cast(half2v, w),
                                  __builtin_bit_cast(half2v, h), acc, false);
#else
    half2v wv = __builtin_bit_cast(half2v, w), hv = __builtin_bit_cast(half2v, h);
    return fmaf((float)wv[1], (float)hv[1], fmaf((float)wv[0], (float)hv[0], acc));
#endif
}
__device__ __forceinline__ u32 hfma2u(u32 w, u32 h, u32 acc) {          // v_pk_fma_f16
    __half2 r = __hfma2(__builtin_bit_cast(__half2, w),
                        __builtin_bit_cast(__half2, h),
                        __builtin_bit_cast(__half2, acc));
    return __builtin_bit_cast(u32, r);
}
__device__ __forceinline__ float pairsum(u32 a) {
    __half2 h = __builtin_bit_cast(__half2, a);
    return __low2float(h) + __high2float(h);
}
// sum across the 4 lanes of a quad — 2 DPP adds
__device__ __forceinline__ float quad_sum(float v) {
    int i = __builtin_bit_cast(int, v);
    v += __builtin_bit_cast(float, __builtin_amdgcn_update_dpp(0, i, 0xB1, 0xF, 0xF, true)); // [1,0,3,2]
    i = __builtin_bit_cast(int, v);
    v += __builtin_bit_cast(float, __builtin_amdgcn_update_dpp(0, i, 0x4E, 0xF, 0xF, true)); // [2,3,0,1]
    return v;
}

// ================= Kernel 1: xi = x @ Wi  (round-3 proven: fdot2, f32 acc) ==
__global__ __launch_bounds__(256, 2) void xi_gemm(const float* __restrict__ x,
                                                  const float* __restrict__ Wi,
                                                  __half* __restrict__ xi) {
    __shared__ u32 xs2[32][128];           // xs2[r][p] = (x[r][2p], x[r][2p+1]) f16
    const int tid = threadIdx.x;
    const int r0  = blockIdx.x * 32;
    {
        const int hi = tid >> 7, lo = tid & 127;
        #pragma unroll
        for (int rr = 0; rr < 16; ++rr) {
            const int r = rr * 2 + hi;
            const float2 v = *(const float2*)&x[(size_t)(r0 + r) * NF + lo * 2];
            xs2[r][lo] = packpair(v.x, v.y);
        }
    }
    __syncthreads();

    float acc[32][3];
    #pragma unroll
    for (int r = 0; r < 32; ++r) { acc[r][0] = 0.f; acc[r][1] = 0.f; acc[r][2] = 0.f; }

    for (int kp2 = 0; kp2 < 64; ++kp2) {   // 4 K-rows per iteration
        const int k = kp2 * 4;
        u32 wA[3], wB[3];
        #pragma unroll
        for (int j = 0; j < 3; ++j) {
            const float* wp = &Wi[(size_t)k * NG + j * 256 + tid];
            wA[j] = packpair(wp[0],              wp[NG]);
            wB[j] = packpair(wp[2 * (size_t)NG], wp[3 * (size_t)NG]);
        }
        #pragma unroll
        for (int r = 0; r < 32; ++r) {
            const uint2 xv = *(const uint2*)&xs2[r][kp2 * 2];   // uniform -> broadcast
            #pragma unroll
            for (int j = 0; j < 3; ++j)
                acc[r][j] = fdot2u(wB[j], xv.y, fdot2u(wA[j], xv.x, acc[r][j]));
        }
    }

    #pragma unroll
    for (int r = 0; r < 32; ++r)
        #pragma unroll
        for (int j = 0; j < 3; ++j)
            xi[(size_t)(r0 + r) * NG + j * 256 + tid] = __float2half(acc[r][j]);
}

// ================= Kernel 2: recurrent scan — ONE block per batch ==========
// 512 threads = (u2 in [0,128), kc = tid&3). Thread owns units {u2, u2+128}
// x 3 gates over k-chunk [64kc, 64kc+64): 192 packed-f16 Wh u32.
// amdgpu_waves_per_eu(2,2): occupancy MAX pinned at 2 waves/EU (exactly our
// single 8-wave block) -> allocator has no incentive to shrink below 256
// arch VGPRs -> wh2 stays architectural, no AGPR shadow reads.
// (__launch_bounds__ 2nd arg is only a MINIMUM promise — rounds 4/5/7 showed
// the allocator still targets 2 blocks/CU and halves the register budget.)
__global__ __attribute__((amdgpu_flat_work_group_size(512, 512),
                          amdgpu_waves_per_eu(2, 2))) void gru_rec(
        const float* __restrict__ carry,
        const __half* __restrict__ xi,
        const float* __restrict__ Wh,
        const float* __restrict__ bh,
        float* __restrict__ out_carry,
        float* __restrict__ out_hidden) {
    __shared__ u32 hsh[2][4][136];     // [buf][replica][128 pairs + pad]

    const int tid = threadIdx.x;
    const int b   = blockIdx.x;
    const int u2  = tid >> 2;          // 0..127 ; owns units u2 and u2+128
    const int kc  = tid & 3;           // k-chunk 0..3
    const int k0  = kc * 64;

    // ---- register-stationary Wh: wh2[uu][j][p] = packed (k0+2p, k0+2p+1)
    u32 wh2[2][3][32];
    #pragma unroll
    for (int uu = 0; uu < 2; ++uu)
        #pragma unroll
        for (int j = 0; j < 3; ++j) {
            const float* wp = &Wh[(size_t)k0 * NG + j * 256 + uu * 128 + u2];
            #pragma unroll
            for (int p = 0; p < 32; ++p) {
                wh2[uu][j][p] = packpair(wp[0], wp[NG]);
                wp += 2 * (size_t)NG;
            }
        }
    const float br0 = bh[u2],       bz0 = bh[256 + u2],       bn0 = bh[512 + u2];
    const float br1 = bh[128 + u2], bz1 = bh[384 + u2], bn1 = bh[640 + u2];

    float h0reg = carry[(size_t)b * NH + u2];
    float h1reg = carry[(size_t)b * NH + 128 + u2];
    ((__half*)&hsh[0][kc][0])[u2]       = __float2half(h0reg);
    ((__half*)&hsh[0][kc][0])[128 + u2] = __float2half(h1reg);

    const __half* xp = xi + (size_t)b * NT * NG;
    __half xr0 = xp[u2],       xz0 = xp[256 + u2],       xn0 = xp[512 + u2];
    __half xr1 = xp[128 + u2], xz1 = xp[384 + u2], xn1 = xp[640 + u2];
    const __half* xq = xp + NG;                 // prefetch cursor (t+1)

    __syncthreads();

#define FMA6(p, hc) { a00 = hfma2u(wh2[0][0][p], hc, a00);  \
                      a01 = hfma2u(wh2[0][1][p], hc, a01);  \
                      a02 = hfma2u(wh2[0][2][p], hc, a02);  \
                      a10 = hfma2u(wh2[1][0][p], hc, a10);  \
                      a11 = hfma2u(wh2[1][1][p], hc, a11);  \
                      a12 = hfma2u(wh2[1][2][p], hc, a12); }

    for (int t = 0; t < NT; ++t) {
        const uint4* hp4 = (const uint4*)&hsh[t & 1][kc][kc * 32];
        u32 a00 = 0, a01 = 0, a02 = 0, a10 = 0, a11 = 0, a12 = 0;
        #pragma unroll
        for (int ph = 0; ph < 4; ++ph) {        // 4 phases x 8 pairs: caps live h regs
            const uint4 hA = hp4[2 * ph], hB = hp4[2 * ph + 1];
            FMA6(8 * ph + 0, hA.x); FMA6(8 * ph + 1, hA.y);
            FMA6(8 * ph + 2, hA.z); FMA6(8 * ph + 3, hA.w);
            FMA6(8 * ph + 4, hB.x); FMA6(8 * ph + 5, hB.y);
            FMA6(8 * ph + 6, hB.z); FMA6(8 * ph + 7, hB.w);
            asm volatile("" ::: "memory");
        }
        const float s00 = quad_sum(pairsum(a00));
        const float s01 = quad_sum(pairsum(a01));
        const float s02 = quad_sum(pairsum(a02));
        const float s10 = quad_sum(pairsum(a10));
        const float s11 = quad_sum(pairsum(a11));
        const float s12 = quad_sum(pairsum(a12));

        // gates (all 4 quad lanes redundantly -> identical f32 results)
        const float rg0 = 1.f / (1.f + __expf(-(__half2float(xr0) + s00 + br0)));
        const float zg0 = 1.f / (1.f + __expf(-(__half2float(xz0) + s01 + bz0)));
        const float tt0 = __half2float(xn0) + rg0 * (s02 + bn0);
        const float ng0 = 1.f - 2.f / (__expf(2.f * tt0) + 1.f);
        const float hn0 = (1.f - zg0) * ng0 + zg0 * h0reg;
        const float rg1 = 1.f / (1.f + __expf(-(__half2float(xr1) + s10 + br1)));
        const float zg1 = 1.f / (1.f + __expf(-(__half2float(xz1) + s11 + bz1)));
        const float tt1 = __half2float(xn1) + rg1 * (s12 + bn1);
        const float ng1 = 1.f - 2.f / (__expf(2.f * tt1) + 1.f);
        const float hn1 = (1.f - zg1) * ng1 + zg1 * h1reg;
        h0reg = hn0; h1reg = hn1;

        if (kc == 0) {
            float* o = out_hidden + ((size_t)b * NT + t) * NH + u2;
            o[0] = hn0; o[128] = hn1;
        }
        ((__half*)&hsh[(t + 1) & 1][kc][0])[u2]       = __float2half(hn0);
        ((__half*)&hsh[(t + 1) & 1][kc][0])[128 + u2] = __float2half(hn1);

        if (t + 1 < NT) {                      // prefetch next xi
            xr0 = xq[u2];       xz0 = xq[256 + u2];       xn0 = xq[512 + u2];
            xr1 = xq[128 + u2]; xz1 = xq[384 + u2]; xn1 = xq[640 + u2];
            xq += NG;
        }
        __syncthreads();
    }
#undef FMA6

    if (kc == 0) {
        out_carry[(size_t)b * NH + u2]       = h0reg;
        out_carry[(size_t)b * NH + 128 + u2] = h1reg;
    }
}

// ================= host =================
extern "C" void kernel_launch(void* const* d_in, const int* in_sizes, int n_in,
                              void* d_out, int out_size, void* d_ws, size_t ws_size,
                              hipStream_t stream) {
    const float* carry = (const float*)d_in[0];
    const float* x     = (const float*)d_in[1];
    const float* Wi    = (const float*)d_in[2];
    const float* Wh    = (const float*)d_in[3];
    const float* bh    = (const float*)d_in[4];

    float* out_carry  = (float*)d_out;
    float* out_hidden = out_carry + (size_t)NB * NH;

    __half* xi = (__half*)d_ws;   // 64*2048*768*2 B = 201.3 MB (fits, proven)

    xi_gemm<<<dim3(NB * NT / 32), dim3(256), 0, stream>>>(x, Wi, xi);
    gru_rec<<<dim3(NB), dim3(512), 0, stream>>>(carry, xi, Wh, bh,
                                                out_carry, out_hidden);
}

// Round 9
// 3380.332 us; speedup vs baseline: 1.0541x; 1.0541x over previous
//
#include <hip/hip_runtime.h>
#include <hip/hip_fp16.h>
#include <stdint.h>

#define NB   64      // batch
#define NT   2048    // time steps
#define NF   256     // input features
#define NH   256     // hidden
#define NG   768     // 3*NH

typedef unsigned int u32;
typedef _Float16 f16;
typedef f16 half2v __attribute__((ext_vector_type(2)));

__device__ __forceinline__ u32 packpair(float a, float b) {
    return __builtin_bit_cast(u32, __builtin_amdgcn_cvt_pkrtz(a, b));   // v_cvt_pkrtz_f16_f32
}
__device__ __forceinline__ float fdot2u(u32 w, u32 h, float acc) {      // f32-acc dot2
#if __has_builtin(__builtin_amdgcn_fdot2)
    return __builtin_amdgcn_fdot2(__builtin_bit_cast(half2v, w),
                                  __builtin_bit_cast(half2v, h), acc, false);
#else
    half2v wv = __builtin_bit_cast(half2v, w), hv = __builtin_bit_cast(half2v, h);
    return fmaf((float)wv[1], (float)hv[1], fmaf((float)wv[0], (float)hv[0], acc));
#endif
}
__device__ __forceinline__ u32 hfma2u(u32 w, u32 h, u32 acc) {          // v_pk_fma_f16
    __half2 r = __hfma2(__builtin_bit_cast(__half2, w),
                        __builtin_bit_cast(__half2, h),
                        __builtin_bit_cast(__half2, acc));
    return __builtin_bit_cast(u32, r);
}
__device__ __forceinline__ float pairsum(u32 a) {
    __half2 h = __builtin_bit_cast(__half2, a);
    return __low2float(h) + __high2float(h);
}
// sum across the 4 lanes of a quad — 2 DPP adds
__device__ __forceinline__ float quad_sum(float v) {
    int i = __builtin_bit_cast(int, v);
    v += __builtin_bit_cast(float, __builtin_amdgcn_update_dpp(0, i, 0xB1, 0xF, 0xF, true)); // [1,0,3,2]
    i = __builtin_bit_cast(int, v);
    v += __builtin_bit_cast(float, __builtin_amdgcn_update_dpp(0, i, 0x4E, 0xF, 0xF, true)); // [2,3,0,1]
    return v;
}

// ====== Kernel 1: xi = x @ Wi (+ r/z biases folded), f16 out ======
__global__ __launch_bounds__(256, 2) void xi_gemm(const float* __restrict__ x,
                                                  const float* __restrict__ Wi,
                                                  const float* __restrict__ bh,
                                                  __half* __restrict__ xi) {
    __shared__ u32 xs2[32][128];           // xs2[r][p] = (x[r][2p], x[r][2p+1]) f16
    const int tid = threadIdx.x;
    const int r0  = blockIdx.x * 32;
    {
        const int hi = tid >> 7, lo = tid & 127;
        #pragma unroll
        for (int rr = 0; rr < 16; ++rr) {
            const int r = rr * 2 + hi;
            const float2 v = *(const float2*)&x[(size_t)(r0 + r) * NF + lo * 2];
            xs2[r][lo] = packpair(v.x, v.y);
        }
    }
    __syncthreads();

    float acc[32][3];
    #pragma unroll
    for (int r = 0; r < 32; ++r) { acc[r][0] = 0.f; acc[r][1] = 0.f; acc[r][2] = 0.f; }

    for (int kp2 = 0; kp2 < 64; ++kp2) {   // 4 K-rows per iteration
        const int k = kp2 * 4;
        u32 wA[3], wB[3];
        #pragma unroll
        for (int j = 0; j < 3; ++j) {
            const float* wp = &Wi[(size_t)k * NG + j * 256 + tid];
            wA[j] = packpair(wp[0],              wp[NG]);
            wB[j] = packpair(wp[2 * (size_t)NG], wp[3 * (size_t)NG]);
        }
        #pragma unroll
        for (int r = 0; r < 32; ++r) {
            const uint2 xv = *(const uint2*)&xs2[r][kp2 * 2];   // uniform -> broadcast
            #pragma unroll
            for (int j = 0; j < 3; ++j)
                acc[r][j] = fdot2u(wB[j], xv.y, fdot2u(wA[j], xv.x, acc[r][j]));
        }
    }

    const float b0 = bh[tid], b1 = bh[256 + tid];   // r/z bias folded (n-bias can't fold)
    #pragma unroll
    for (int r = 0; r < 32; ++r) {
        __half* xo = &xi[(size_t)(r0 + r) * NG];
        xo[tid]       = __float2half(acc[r][0] + b0);
        xo[256 + tid] = __float2half(acc[r][1] + b1);
        xo[512 + tid] = __float2half(acc[r][2]);
    }
}

// ====== Kernel 2: recurrent scan — 64 blocks x 1024 threads ======
// Thread = (u in [0,256), kc = tid&3): 1 unit x 3 gates x 64 k -> 96 packed
// Wh u32 + ~30 working regs = fits the 128-VGPR cap that 16 waves/CU
// implies. This WORKS WITH the allocator's observed fixed point (it chose a
// 128 budget in every prior round) instead of fighting for 192 arch regs.
// waves_per_eu(4,4) pins 1 block/CU (round 4 failed because the allocator
// targeted 2 blocks/CU = 32 waves = 64-reg cap -> AGPR shadowing).
// Bank-exact replica LDS: reads hit disjoint bank-quads {0,8,16,24} with
// 16-lane broadcast; writes tile all 32 banks. One barrier per step.
__global__ __attribute__((amdgpu_flat_work_group_size(1024, 1024),
                          amdgpu_waves_per_eu(4, 4))) void gru_rec(
        const float* __restrict__ carry,
        const __half* __restrict__ xi,
        const float* __restrict__ Wh,
        const float* __restrict__ bh,
        float* __restrict__ out_carry,
        float* __restrict__ out_hidden) {
    __shared__ u32 hsh[2][4][136];     // [buf][replica][128 pairs + pad]

    const int tid = threadIdx.x;
    const int b   = blockIdx.x;
    const int u   = tid >> 2;          // unit 0..255
    const int kc  = tid & 3;           // k-chunk 0..3
    const int k0  = kc * 64;

    // ---- register-stationary Wh: wh2[j][p] = packed (k0+2p, k0+2p+1) of col j*256+u
    u32 wh2[3][32];
    #pragma unroll
    for (int j = 0; j < 3; ++j) {
        const float* wp = &Wh[(size_t)k0 * NG + j * 256 + u];
        #pragma unroll
        for (int p = 0; p < 32; ++p) {
            wh2[j][p] = packpair(wp[0], wp[NG]);
            wp += 2 * (size_t)NG;
        }
    }
    const float bn = bh[512 + u];      // only the n-gate bias survives un-folded

    float hreg = carry[(size_t)b * NH + u];
    ((__half*)&hsh[0][kc][0])[u] = __float2half(hreg);

    const __half* xq = xi + (size_t)b * NT * NG;
    __half xr = xq[u], xz = xq[256 + u], xn = xq[512 + u];
    xq += NG;                          // prefetch cursor (t+1)
    float* op = out_hidden + (size_t)b * NT * NH + u;

    __syncthreads();

#define FMA3(p, hc) { a0 = hfma2u(wh2[0][p], hc, a0); \
                      a1 = hfma2u(wh2[1][p], hc, a1); \
                      a2 = hfma2u(wh2[2][p], hc, a2); }

    for (int t = 0; t < NT; ++t) {
        const uint4* hp4 = (const uint4*)&hsh[t & 1][kc][kc * 32];
        u32 a0 = 0, a1 = 0, a2 = 0;
        #pragma unroll
        for (int ph = 0; ph < 4; ++ph) {        // 4 phases x 8 pairs: caps live h regs
            const uint4 hA = hp4[2 * ph], hB = hp4[2 * ph + 1];
            FMA3(8 * ph + 0, hA.x); FMA3(8 * ph + 1, hA.y);
            FMA3(8 * ph + 2, hA.z); FMA3(8 * ph + 3, hA.w);
            FMA3(8 * ph + 4, hB.x); FMA3(8 * ph + 5, hB.y);
            FMA3(8 * ph + 6, hB.z); FMA3(8 * ph + 7, hB.w);
            asm volatile("" ::: "memory");
        }
        const float s0 = quad_sum(pairsum(a0));
        const float s1 = quad_sum(pairsum(a1));
        const float s2 = quad_sum(pairsum(a2));

        // gates: all 4 quad lanes redundantly (identical f32 ops -> identical results)
        const float rg = 1.f / (1.f + __expf(-(__half2float(xr) + s0)));  // bias folded
        const float zg = 1.f / (1.f + __expf(-(__half2float(xz) + s1)));  // bias folded
        const float tt = __half2float(xn) + rg * (s2 + bn);
        const float ng = 1.f - 2.f / (__expf(2.f * tt) + 1.f);
        const float hn = (1.f - zg) * ng + zg * hreg;
        hreg = hn;

        if (kc == 0) *op = hn;
        op += NH;
        ((__half*)&hsh[(t + 1) & 1][kc][0])[u] = __float2half(hn);   // lane kc -> replica kc

        if (t + 1 < NT) {                      // single-step xi prefetch (3 regs)
            xr = xq[u]; xz = xq[256 + u]; xn = xq[512 + u];
            xq += NG;
        }
        __syncthreads();
    }
#undef FMA3

    if (kc == 0) out_carry[(size_t)b * NH + u] = hreg;
}

// ================= host =================
extern "C" void kernel_launch(void* const* d_in, const int* in_sizes, int n_in,
                              void* d_out, int out_size, void* d_ws, size_t ws_size,
                              hipStream_t stream) {
    const float* carry = (const float*)d_in[0];
    const float* x     = (const float*)d_in[1];
    const float* Wi    = (const float*)d_in[2];
    const float* Wh    = (const float*)d_in[3];
    const float* bh    = (const float*)d_in[4];

    float* out_carry  = (float*)d_out;
    float* out_hidden = out_carry + (size_t)NB * NH;

    __half* xi = (__half*)d_ws;   // 64*2048*768*2 B = 201.3 MB (fits, proven)

    xi_gemm<<<dim3(NB * NT / 32), dim3(256), 0, stream>>>(x, Wi, bh, xi);
    gru_rec<<<dim3(NB), dim3(1024), 0, stream>>>(carry, xi, Wh, bh,
                                                 out_carry, out_hidden);
}

// Round 10
// 2822.064 us; speedup vs baseline: 1.2626x; 1.1978x over previous
//
#include <hip/hip_runtime.h>
#include <hip/hip_fp16.h>
#include <stdint.h>

#define NB   64      // batch
#define NT   2048    // time steps
#define NF   256     // input features
#define NH   256     // hidden
#define NG   768     // 3*NH
#define NPROD 192    // producer blocks (xi GEMM)
#define GRPT  16     // timesteps per ticket group (128 groups)

typedef unsigned int u32;
typedef _Float16 f16;
typedef f16 half2v __attribute__((ext_vector_type(2)));

__device__ __forceinline__ u32 packpair(float a, float b) {
    return __builtin_bit_cast(u32, __builtin_amdgcn_cvt_pkrtz(a, b));   // v_cvt_pkrtz_f16_f32
}
__device__ __forceinline__ float fdot2u(u32 w, u32 h, float acc) {      // f32-acc dot2
#if __has_builtin(__builtin_amdgcn_fdot2)
    return __builtin_amdgcn_fdot2(__builtin_bit_cast(half2v, w),
                                  __builtin_bit_cast(half2v, h), acc, false);
#else
    half2v wv = __builtin_bit_cast(half2v, w), hv = __builtin_bit_cast(half2v, h);
    return fmaf((float)wv[1], (float)hv[1], fmaf((float)wv[0], (float)hv[0], acc));
#endif
}
__device__ __forceinline__ u32 hfma2u(u32 w, u32 h, u32 acc) {          // v_pk_fma_f16
    __half2 r = __hfma2(__builtin_bit_cast(__half2, w),
                        __builtin_bit_cast(__half2, h),
                        __builtin_bit_cast(__half2, acc));
    return __builtin_bit_cast(u32, r);
}
__device__ __forceinline__ float pairsum(u32 a) {
    __half2 h = __builtin_bit_cast(__half2, a);
    return __low2float(h) + __high2float(h);
}
__device__ __forceinline__ float halfsel(u32 w, int hi) {
    half2v h = __builtin_bit_cast(half2v, w);
    return (float)h[hi & 1];
}
// sum across the 4 lanes of a quad — 2 DPP adds
__device__ __forceinline__ float quad_sum(float v) {
    int i = __builtin_bit_cast(int, v);
    v += __builtin_bit_cast(float, __builtin_amdgcn_update_dpp(0, i, 0xB1, 0xF, 0xF, true)); // [1,0,3,2]
    i = __builtin_bit_cast(int, v);
    v += __builtin_bit_cast(float, __builtin_amdgcn_update_dpp(0, i, 0x4E, 0xF, 0xF, true)); // [2,3,0,1]
    return v;
}

// ============ Fused kernel: 256 blocks x 1024 threads ============
// blocks [64,256): PRODUCERS — xi[b][t][:] = x[b][t]@Wi (+r/z bias), written
//   as agent-scope atomic u32 stores (coherence point = L3; consumer L2s are
//   not coherent so plain stores would be invisible). Producer p handles
//   t = p, p+192, ... After each t: barrier (drains vmcnt in every wave) then
//   RELEASE fetch_add on groups[t/16]. Producers never wait on consumers.
// blocks [0,64): CONSUMERS — the round-9 recurrent scan; before touching xi
//   of group g it ACQUIRE-polls groups[g]==16 (once per 16 steps; the acquire
//   invalidates L1/L2 so subsequent regular loads observe the atomic stores,
//   including across graph replays over poisoned/stale cache lines).
__global__ __attribute__((amdgpu_flat_work_group_size(1024, 1024),
                          amdgpu_waves_per_eu(4, 4))) void gru_fused(
        const float* __restrict__ carry,
        const float* __restrict__ x,
        const float* __restrict__ Wi,
        const float* __restrict__ Wh,
        const float* __restrict__ bh,
        f16*   __restrict__ xi,
        int*   __restrict__ groups,
        float* __restrict__ out_carry,
        float* __restrict__ out_hidden) {
    const int tid = threadIdx.x;

    if (blockIdx.x >= NB) {
        // ======================= PRODUCER =======================
        __shared__ u32 xs2[16][128];                  // 16 rows, packed f16 pairs
        __shared__ unsigned short ost[16][768];       // pass output stage
        const int p = blockIdx.x - NB;

        for (int t = p; t < NT; t += NPROD) {
            #pragma unroll 1
            for (int pass = 0; pass < 4; ++pass) {    // 16 batches per pass
                const int b0 = pass * 16;
                for (int i = tid; i < 16 * 128; i += 1024) {
                    const int r = i >> 7, pc = i & 127;
                    const float2 v = *(const float2*)&x[((size_t)(b0 + r) * NT + t) * NF + pc * 2];
                    xs2[r][pc] = packpair(v.x, v.y);
                }
                __syncthreads();

                if (tid < NG) {
                    float acc[16];
                    #pragma unroll
                    for (int r = 0; r < 16; ++r) acc[r] = 0.f;
                    for (int kp = 0; kp < 128; ++kp) {
                        const u32 wp = packpair(Wi[(size_t)(2 * kp) * NG + tid],
                                                Wi[(size_t)(2 * kp + 1) * NG + tid]);
                        #pragma unroll
                        for (int r = 0; r < 16; ++r)
                            acc[r] = fdot2u(wp, xs2[r][kp], acc[r]);
                    }
                    const float bias = (tid < 512) ? bh[tid] : 0.f;   // fold r/z bias
                    #pragma unroll
                    for (int r = 0; r < 16; ++r)
                        ost[r][tid] = (unsigned short)__builtin_bit_cast(unsigned short, (f16)(acc[r] + bias));
                }
                __syncthreads();

                // pack to u32 and atomic-store (L3 coherence point)
                for (int i = tid; i < 16 * 384; i += 1024) {
                    const int r = i / 384, j = i - r * 384;
                    const u32 v = ((const u32*)&ost[r][0])[j];
                    __hip_atomic_store((u32*)xi + ((size_t)(b0 + r) * NT + t) * 384 + j,
                                       v, __ATOMIC_RELAXED, __HIP_MEMORY_SCOPE_AGENT);
                }
                __syncthreads();   // every wave drains vmcnt here (stores complete)
            }
            if (tid == 0)
                __hip_atomic_fetch_add(&groups[t >> 4], 1,
                                       __ATOMIC_RELEASE, __HIP_MEMORY_SCOPE_AGENT);
        }
        return;
    }

    // ======================= CONSUMER =======================
    __shared__ u32 hsh[2][4][136];     // [buf][replica][128 pairs + pad]
    const int b   = blockIdx.x;
    const int u   = tid >> 2;          // unit 0..255
    const int kc  = tid & 3;           // k-chunk 0..3
    const int k0  = kc * 64;

    // register-stationary Wh: wh2[j][p] = packed (k0+2p, k0+2p+1) of col j*256+u
    u32 wh2[3][32];
    #pragma unroll
    for (int j = 0; j < 3; ++j) {
        const float* wp = &Wh[(size_t)k0 * NG + j * 256 + u];
        #pragma unroll
        for (int pp = 0; pp < 32; ++pp) {
            wh2[j][pp] = packpair(wp[0], wp[NG]);
            wp += 2 * (size_t)NG;
        }
    }
    const float bn = bh[512 + u];

    float hreg = carry[(size_t)b * NH + u];
    ((f16*)&hsh[0][kc][0])[u] = (f16)hreg;

    // wait for xi group 0, then load t=0
    if (tid == 0) {
        while (__hip_atomic_load(&groups[0], __ATOMIC_ACQUIRE, __HIP_MEMORY_SCOPE_AGENT) < GRPT)
            __builtin_amdgcn_s_sleep(2);
    }
    __syncthreads();

    const u32* xb32 = (const u32*)xi + (size_t)b * NT * 384;
    const int  uh   = u >> 1, us = u & 1;
    u32 wr = xb32[uh], wz = xb32[128 + uh], wn = xb32[256 + uh];
    float* op = out_hidden + (size_t)b * NT * NH + u;

#define FMA3(p, hc) { a0 = hfma2u(wh2[0][p], hc, a0); \
                      a1 = hfma2u(wh2[1][p], hc, a1); \
                      a2 = hfma2u(wh2[2][p], hc, a2); }

    for (int t = 0; t < NT; ++t) {
        // poll next xi group at its boundary (amortized ~once/16 steps)
        if (((t + 1) & (GRPT - 1)) == 0 && t + 1 < NT) {
            if (tid == 0) {
                while (__hip_atomic_load(&groups[(t + 1) >> 4], __ATOMIC_ACQUIRE,
                                         __HIP_MEMORY_SCOPE_AGENT) < GRPT)
                    __builtin_amdgcn_s_sleep(2);
            }
            __syncthreads();
        }

        const uint4* hp4 = (const uint4*)&hsh[t & 1][kc][kc * 32];
        u32 a0 = 0, a1 = 0, a2 = 0;
        #pragma unroll
        for (int ph = 0; ph < 4; ++ph) {
            const uint4 hA = hp4[2 * ph], hB = hp4[2 * ph + 1];
            FMA3(8 * ph + 0, hA.x); FMA3(8 * ph + 1, hA.y);
            FMA3(8 * ph + 2, hA.z); FMA3(8 * ph + 3, hA.w);
            FMA3(8 * ph + 4, hB.x); FMA3(8 * ph + 5, hB.y);
            FMA3(8 * ph + 6, hB.z); FMA3(8 * ph + 7, hB.w);
        }
        const float s0 = quad_sum(pairsum(a0));
        const float s1 = quad_sum(pairsum(a1));
        const float s2 = quad_sum(pairsum(a2));

        // gates (all 4 quad lanes redundantly -> identical f32 results)
        const float rg = __builtin_amdgcn_rcpf(1.f + __expf(-(halfsel(wr, us) + s0)));
        const float zg = __builtin_amdgcn_rcpf(1.f + __expf(-(halfsel(wz, us) + s1)));
        const float tt = halfsel(wn, us) + rg * (s2 + bn);
        const float ng = 1.f - 2.f * __builtin_amdgcn_rcpf(1.f + __expf(2.f * tt));
        const float hn = ng + zg * (hreg - ng);
        hreg = hn;

        if (kc == 0) *op = hn;
        op += NH;
        ((f16*)&hsh[(t + 1) & 1][kc][0])[u] = (f16)hn;   // lane kc -> replica kc

        if (t + 1 < NT) {                                // prefetch next xi (u32)
            const size_t base = (size_t)(t + 1) * 384;
            wr = xb32[base + uh]; wz = xb32[base + 128 + uh]; wn = xb32[base + 256 + uh];
        }
        __syncthreads();
    }
#undef FMA3

    if (kc == 0) out_carry[(size_t)b * NH + u] = hreg;
}

// ================= host =================
extern "C" void kernel_launch(void* const* d_in, const int* in_sizes, int n_in,
                              void* d_out, int out_size, void* d_ws, size_t ws_size,
                              hipStream_t stream) {
    const float* carry = (const float*)d_in[0];
    const float* x     = (const float*)d_in[1];
    const float* Wi    = (const float*)d_in[2];
    const float* Wh    = (const float*)d_in[3];
    const float* bh    = (const float*)d_in[4];

    float* out_carry  = (float*)d_out;
    float* out_hidden = out_carry + (size_t)NB * NH;

    const size_t XI_BYTES = (size_t)NB * NT * NG * 2;   // 201.3 MB (fits, proven)
    f16* xi     = (f16*)d_ws;
    int* groups = (int*)((char*)d_ws + XI_BYTES);       // 128 group counters

    hipMemsetAsync(groups, 0, 128 * sizeof(int), stream);
    gru_fused<<<dim3(NB + NPROD), dim3(1024), 0, stream>>>(
        carry, x, Wi, Wh, bh, xi, groups, out_carry, out_hidden);
}

// Round 11
// 2517.755 us; speedup vs baseline: 1.4152x; 1.1209x over previous
//
#include <hip/hip_runtime.h>
#include <hip/hip_fp16.h>
#include <stdint.h>

#define NB    64      // batch
#define NT    2048    // time steps
#define NF    256     // input features
#define NH    256     // hidden
#define NG    768     // 3*NH
#define NPROD 192     // producer blocks (xi GEMM)
#define GRPT  16      // timesteps per ticket group
#define NGRP  (NT / GRPT)

typedef unsigned int u32;
typedef _Float16 f16;
typedef f16 half2v __attribute__((ext_vector_type(2)));
typedef float f32x4a4 __attribute__((ext_vector_type(4), aligned(4)));  // 4B-aligned dwordx4

__device__ __forceinline__ u32 packpair(float a, float b) {
    return __builtin_bit_cast(u32, __builtin_amdgcn_cvt_pkrtz(a, b));   // v_cvt_pkrtz_f16_f32
}
__device__ __forceinline__ float fdot2u(u32 w, u32 h, float acc) {      // f32-acc dot2
#if __has_builtin(__builtin_amdgcn_fdot2)
    return __builtin_amdgcn_fdot2(__builtin_bit_cast(half2v, w),
                                  __builtin_bit_cast(half2v, h), acc, false);
#else
    half2v wv = __builtin_bit_cast(half2v, w), hv = __builtin_bit_cast(half2v, h);
    return fmaf((float)wv[1], (float)hv[1], fmaf((float)wv[0], (float)hv[0], acc));
#endif
}
// sum across the 4 lanes of a quad — 2 DPP adds
__device__ __forceinline__ float quad_sum(float v) {
    int i = __builtin_bit_cast(int, v);
    v += __builtin_bit_cast(float, __builtin_amdgcn_update_dpp(0, i, 0xB1, 0xF, 0xF, true)); // [1,0,3,2]
    i = __builtin_bit_cast(int, v);
    v += __builtin_bit_cast(float, __builtin_amdgcn_update_dpp(0, i, 0x4E, 0xF, 0xF, true)); // [2,3,0,1]
    return v;
}

// ============ Fused kernel: 256 blocks x 1024 threads ============
// blocks [64,256): PRODUCERS — xi[b][t][u][g] = (x[b][t]@Wi)[g*256+u] (+r/z
//   bias), f32, UNIT-INTERLEAVED so consumers read one dwordx4 per step.
//   Written as agent-scope relaxed atomic u32 stores (coherence point = L3;
//   consumer L2s are not cross-coherent), then barrier (drains vmcnt) and a
//   RELEASE fetch_add on groups[t/16]. Producers never wait on consumers.
// blocks [0,64): CONSUMERS — round-9/10 scan, 16-step-unrolled groups.
//   Group g's steps prefetch xi up to t=16g+16 (group g+1), so before group
//   g runs, groups[g] AND groups[g+1] must be complete: poll 0,1 up front,
//   then poll g+2 after finishing group g. ACQUIRE invalidates L1/L2 so the
//   plain xi loads that follow observe producer stores (incl. across graph
//   replays; groups[] is memset on-stream each launch).
__global__ __attribute__((amdgpu_flat_work_group_size(1024, 1024),
                          amdgpu_waves_per_eu(4, 4))) void gru_fused(
        const float* __restrict__ carry,
        const float* __restrict__ x,
        const float* __restrict__ Wi,
        const float* __restrict__ Wh,
        const float* __restrict__ bh,
        float* __restrict__ xi,        // f32, [b][t][u][3] interleaved
        int*   __restrict__ groups,
        float* __restrict__ out_carry,
        float* __restrict__ out_hidden) {
    const int tid = threadIdx.x;

    if (blockIdx.x >= NB) {
        // ======================= PRODUCER =======================
        __shared__ u32 xs2[16][128];                  // 16 rows, packed f16 pairs
        const int p = blockIdx.x - NB;

        for (int t = p; t < NT; t += NPROD) {
            #pragma unroll 1
            for (int pass = 0; pass < 4; ++pass) {    // 16 batches per pass
                const int b0 = pass * 16;
                for (int i = tid; i < 16 * 128; i += 1024) {
                    const int r = i >> 7, pc = i & 127;
                    const float2 v = *(const float2*)&x[((size_t)(b0 + r) * NT + t) * NF + pc * 2];
                    xs2[r][pc] = packpair(v.x, v.y);
                }
                __syncthreads();

                if (tid < NG) {
                    float acc[16];
                    #pragma unroll
                    for (int r = 0; r < 16; ++r) acc[r] = 0.f;
                    for (int kp = 0; kp < 128; ++kp) {
                        const u32 wp = packpair(Wi[(size_t)(2 * kp) * NG + tid],
                                                Wi[(size_t)(2 * kp + 1) * NG + tid]);
                        #pragma unroll
                        for (int r = 0; r < 16; ++r)
                            acc[r] = fdot2u(wp, xs2[r][kp], acc[r]);
                    }
                    const float bias = (tid < 512) ? bh[tid] : 0.f;   // fold r/z bias
                    const int g3 = tid >> 8;          // gate 0..2
                    const int un = tid & 255;         // unit
                    #pragma unroll
                    for (int r = 0; r < 16; ++r) {
                        const u32 v = __builtin_bit_cast(u32, acc[r] + bias);
                        __hip_atomic_store((u32*)xi + ((size_t)(b0 + r) * NT + t) * NG + un * 3 + g3,
                                           v, __ATOMIC_RELAXED, __HIP_MEMORY_SCOPE_AGENT);
                    }
                }
                __syncthreads();   // waves done reading xs2 + vmcnt drained
            }
            if (tid == 0)
                __hip_atomic_fetch_add(&groups[t >> 4], 1,
                                       __ATOMIC_RELEASE, __HIP_MEMORY_SCOPE_AGENT);
        }
        return;
    }

    // ======================= CONSUMER =======================
    __shared__ u32 hsh[2][4][136];     // [buf][replica][128 pairs + pad]
    const int b   = blockIdx.x;
    const int u   = tid >> 2;          // unit 0..255
    const int kc  = tid & 3;           // k-chunk 0..3
    const int k0  = kc * 64;

    // register-stationary Wh: wh2[j][p] = packed (k0+2p, k0+2p+1) of col j*256+u
    u32 wh2[3][32];
    #pragma unroll
    for (int j = 0; j < 3; ++j) {
        const float* wp = &Wh[(size_t)k0 * NG + j * 256 + u];
        #pragma unroll
        for (int pp = 0; pp < 32; ++pp) {
            wh2[j][pp] = packpair(wp[0], wp[NG]);
            wp += 2 * (size_t)NG;
        }
    }
    const float bn = bh[512 + u];

    float hreg = carry[(size_t)b * NH + u];
    ((f16*)&hsh[0][kc][0])[u] = (f16)hreg;

    // wait for xi groups 0 and 1 (group 0's steps prefetch into group 1)
    if (tid == 0) {
        while (__hip_atomic_load(&groups[0], __ATOMIC_ACQUIRE, __HIP_MEMORY_SCOPE_AGENT) < GRPT)
            __builtin_amdgcn_s_sleep(2);
        while (__hip_atomic_load(&groups[1], __ATOMIC_ACQUIRE, __HIP_MEMORY_SCOPE_AGENT) < GRPT)
            __builtin_amdgcn_s_sleep(2);
    }
    __syncthreads();

    const float* xq = xi + (size_t)b * NT * NG + u * 3;
    f32x4a4 xv = *(const f32x4a4*)xq;          // one dwordx4: (r, z, n, -)
    xq += NG;
    float xr = xv[0], xz = xv[1], xn = xv[2];
    float* op = out_hidden + (size_t)b * NT * NH + u;

#define D3(p, hc) { a0 = fdot2u(wh2[0][p], hc, a0); \
                    a1 = fdot2u(wh2[1][p], hc, a1); \
                    a2 = fdot2u(wh2[2][p], hc, a2); }

    for (int g = 0; g < NGRP; ++g) {
        #pragma unroll
        for (int j = 0; j < GRPT; ++j) {       // fully unrolled: parity static
            const int RB = j & 1, WB = RB ^ 1;
            const uint4* hp4 = (const uint4*)&hsh[RB][kc][kc * 32];
            float a0 = 0.f, a1 = 0.f, a2 = 0.f;
            #pragma unroll
            for (int ph = 0; ph < 4; ++ph) {
                const uint4 hA = hp4[2 * ph], hB = hp4[2 * ph + 1];
                D3(8 * ph + 0, hA.x); D3(8 * ph + 1, hA.y);
                D3(8 * ph + 2, hA.z); D3(8 * ph + 3, hA.w);
                D3(8 * ph + 4, hB.x); D3(8 * ph + 5, hB.y);
                D3(8 * ph + 6, hB.z); D3(8 * ph + 7, hB.w);
            }
            a0 = quad_sum(a0); a1 = quad_sum(a1); a2 = quad_sum(a2);

            // gates (all 4 quad lanes redundantly -> identical f32 results)
            const float rg = __builtin_amdgcn_rcpf(1.f + __expf(-(xr + a0)));
            const float zg = __builtin_amdgcn_rcpf(1.f + __expf(-(xz + a1)));
            const float tt = xn + rg * (a2 + bn);
            const float ng = 1.f - 2.f * __builtin_amdgcn_rcpf(1.f + __expf(2.f * tt));
            const float hn = ng + zg * (hreg - ng);
            hreg = hn;

            if (kc == 0) *op = hn;
            op += NH;
            ((f16*)&hsh[WB][kc][0])[u] = (f16)hn;   // lane kc -> replica kc

            xv = *(const f32x4a4*)xq;               // prefetch t+1 (slack after xi end)
            xq += NG;
            xr = xv[0]; xz = xv[1]; xn = xv[2];
            __syncthreads();
        }
        if (g + 2 < NGRP) {                         // next group prefetches into g+2
            if (tid == 0) {
                while (__hip_atomic_load(&groups[g + 2], __ATOMIC_ACQUIRE,
                                         __HIP_MEMORY_SCOPE_AGENT) < GRPT)
                    __builtin_amdgcn_s_sleep(2);
            }
            __syncthreads();
        }
    }
#undef D3

    if (kc == 0) out_carry[(size_t)b * NH + u] = hreg;
}

// ================= host =================
extern "C" void kernel_launch(void* const* d_in, const int* in_sizes, int n_in,
                              void* d_out, int out_size, void* d_ws, size_t ws_size,
                              hipStream_t stream) {
    const float* carry = (const float*)d_in[0];
    const float* x     = (const float*)d_in[1];
    const float* Wi    = (const float*)d_in[2];
    const float* Wh    = (const float*)d_in[3];
    const float* bh    = (const float*)d_in[4];

    float* out_carry  = (float*)d_out;
    float* out_hidden = out_carry + (size_t)NB * NH;

    // layout: [groups: 512B @0] [pad to 4KB] [xi f32: 402.7MB] [slack]
    // (ws >= 402MB + 0.5MB proven by round 1's mode-0 run)
    int*   groups = (int*)d_ws;
    float* xi     = (float*)((char*)d_ws + 4096);

    hipMemsetAsync(groups, 0, NGRP * sizeof(int), stream);
    gru_fused<<<dim3(NB + NPROD), dim3(1024), 0, stream>>>(
        carry, x, Wi, Wh, bh, xi, groups, out_carry, out_hidden);
}